// Round 7
// baseline (1435.235 us; speedup 1.0000x reference)
//
#include <hip/hip_runtime.h>

#define BB 128
#define TT 2048
#define II 64
#define HH 128

typedef _Float16 h2 __attribute__((ext_vector_type(2)));
typedef _Float16 f16x8 __attribute__((ext_vector_type(8)));
typedef float f32x4 __attribute__((ext_vector_type(4)));

__device__ __forceinline__ h2 mkh2(float a, float b) {
    h2 r; r.x = (_Float16)a; r.y = (_Float16)b; return r;
}

__device__ __forceinline__ h2 u2h(unsigned u) {
    return __builtin_bit_cast(h2, u);
}

__device__ __forceinline__ float fdot2f(h2 a, h2 b, float c) {
#if __has_builtin(__builtin_amdgcn_fdot2)
    return __builtin_amdgcn_fdot2(a, b, c, false);
#else
    return fmaf((float)a.y, (float)b.y, fmaf((float)a.x, (float)b.x, c));
#endif
}

__device__ __forceinline__ float rcp_fast(float x) {
    return __builtin_amdgcn_rcpf(x);
}

__device__ __forceinline__ float tanh_fast(float x) {
    return fmaf(rcp_fast(1.0f + __expf(-2.0f * x)), 2.0f, -1.0f);
}

__device__ __forceinline__ float sigmoid_fast(float x) {
    return rcp_fast(1.0f + __expf(-x));
}

__device__ __forceinline__ f16x8 ld_frag(const void* p) {
    return __builtin_bit_cast(f16x8, *reinterpret_cast<const uint4*>(p));
}

// ---------------------------------------------------------------------------
// Phase 1: xproj[b][t][row] = dot(input[b][t][:], W_ih[row][:]) + b_ih + b_hh
// (fp16). Massively parallel: grid = B * T/32 blocks x 512 threads; thread
// owns one weight row, loops 32 timesteps staged in LDS.
// ---------------------------------------------------------------------------
__global__ __launch_bounds__(512, 2) void xproj_kernel(
    const float* __restrict__ input,  // [B,T,I]
    const float* __restrict__ W_ih,   // [4H,I]
    const float* __restrict__ b_ih,   // [4H]
    const float* __restrict__ b_hh,   // [4H]
    _Float16* __restrict__ xproj)     // [B,T,4H]
{
    __shared__ __align__(16) h2 sx[32][II / 2];   // 32 timesteps x 64 halfs

    const int tid = threadIdx.x;        // = weight row 0..511
    const int bt  = blockIdx.x;
    const int b   = bt >> 6;            // T/32 = 64 tiles per batch
    const int tt  = (bt & 63) << 5;

    // weight row -> 32 h2 regs
    h2 wr[II / 2];
    {
        const float4* p = reinterpret_cast<const float4*>(W_ih + (size_t)tid * II);
#pragma unroll
        for (int q = 0; q < II / 4; ++q) {
            float4 v = p[q];
            wr[2 * q]     = mkh2(v.x, v.y);
            wr[2 * q + 1] = mkh2(v.z, v.w);
        }
    }
    const float bias = b_ih[tid] + b_hh[tid];

    // stage x tile: 32 t x 64 f32 = 2048 f32; thread loads one float4
    {
        const int tl = tid >> 4, k4 = tid & 15;
        float4 v = *reinterpret_cast<const float4*>(
            input + ((size_t)b * TT + tt + tl) * II + 4 * k4);
        h2* dst = &sx[tl][2 * k4];
        dst[0] = mkh2(v.x, v.y);
        dst[1] = mkh2(v.z, v.w);
    }
    __syncthreads();

    _Float16* op = xproj + ((size_t)b * TT + tt) * 512 + tid;
#pragma unroll 4
    for (int tl = 0; tl < 32; ++tl) {
        const uint4* xr = reinterpret_cast<const uint4*>(&sx[tl][0]);
        float a0 = bias, a1 = 0.f, a2 = 0.f, a3 = 0.f;
#pragma unroll
        for (int q = 0; q < 8; ++q) {
            uint4 v = xr[q];
            a0 = fdot2f(wr[4 * q + 0], u2h(v.x), a0);
            a1 = fdot2f(wr[4 * q + 1], u2h(v.y), a1);
            a2 = fdot2f(wr[4 * q + 2], u2h(v.z), a2);
            a3 = fdot2f(wr[4 * q + 3], u2h(v.w), a3);
        }
        op[(size_t)tl * 512] = (_Float16)((a0 + a1) + (a2 + a3));
    }
}

// ---------------------------------------------------------------------------
// Phase 2: recurrence only. Per step: 16 MFMAs (W_hh*h), acc seeded from the
// precomputed x-projection (prefetched 2 steps ahead into registers).
// Layouts (16x16x32_f16, validated r5): A row=lane&15, k=8*(lane>>4)+i;
// B col=lane&15 (broadcast); D col=lane&15, row=4*(lane>>4)+reg.
// ---------------------------------------------------------------------------
struct XPF { uint2 q0, q1, q2, q3; };   // 4 gates x 4 fp16 (rows jb..jb+3)

__device__ __forceinline__ XPF ldxp(const _Float16* xpb, int t, int jb) {
    const char* p = reinterpret_cast<const char*>(xpb) + ((size_t)t * 512 + jb) * 2;
    XPF r;
    r.q0 = *reinterpret_cast<const uint2*>(p);
    r.q1 = *reinterpret_cast<const uint2*>(p + 256);
    r.q2 = *reinterpret_cast<const uint2*>(p + 512);
    r.q3 = *reinterpret_cast<const uint2*>(p + 768);
    return r;
}

__device__ __forceinline__ f32x4 cvtq(uint2 q) {
    h2 a = __builtin_bit_cast(h2, q.x), b = __builtin_bit_cast(h2, q.y);
    f32x4 r;
    r[0] = (float)a.x; r[1] = (float)a.y; r[2] = (float)b.x; r[3] = (float)b.y;
    return r;
}

__global__ __launch_bounds__(512, 2) void lstm_rec_kernel(
    const _Float16* __restrict__ xproj,  // [B,T,4H] incl. biases
    const float* __restrict__ h0,        // [B,H]
    const float* __restrict__ c0,        // [B,H]
    const float* __restrict__ W_hh,      // [4H,H]
    float* __restrict__ out)             // [B*H] h_last, then [B,T,H]
{
    __shared__ __align__(16) h2 s_h[2][HH / 2];   // h double buffer

    const int tid  = threadIdx.x;
    const int b    = blockIdx.x;
    const int lane = tid & 63;
    const int w    = tid >> 6;
    const int grp  = lane >> 4;
    const int m    = lane & 15;
    const int r    = lane & 3;
    const int jb   = (w << 4) | (grp << 2);
    const int jown = jb | r;

    // A-fragments: W_hh only (4 K-tiles), fp32 -> fp16
    f16x8 wfh[4][4];   // 64 VGPR
#pragma unroll
    for (int g = 0; g < 4; ++g) {
        const int row = (g << 7) | (w << 4) | m;
#pragma unroll
        for (int kt = 0; kt < 4; ++kt) {
            const float* src = W_hh + (size_t)row * HH + 32 * kt + 8 * grp;
            const float4 v0 = reinterpret_cast<const float4*>(src)[0];
            const float4 v1 = reinterpret_cast<const float4*>(src)[1];
            f16x8 f;
            f[0] = (_Float16)v0.x; f[1] = (_Float16)v0.y;
            f[2] = (_Float16)v0.z; f[3] = (_Float16)v0.w;
            f[4] = (_Float16)v1.x; f[5] = (_Float16)v1.y;
            f[6] = (_Float16)v1.z; f[7] = (_Float16)v1.w;
            wfh[g][kt] = f;
        }
    }

    float c = c0[(size_t)b * HH + jown];
    if (tid < 64) {
        float2 hv = reinterpret_cast<const float2*>(h0 + (size_t)b * HH)[tid];
        s_h[0][tid] = mkh2(hv.x, hv.y);
    }

    const _Float16* xpb = xproj + (size_t)b * TT * 512;
    XPF xf0 = ldxp(xpb, 0, jb);
    XPF xf1 = ldxp(xpb, 1, jb);
    __syncthreads();

    float* out_h = out;
    float* out_e = out + BB * HH;
    float hlast = 0.0f;
    const bool writer = (lane & 12) == 0;

    auto step = [&](int t, XPF& xp) {
        const int cb = t & 1, nb = cb ^ 1;

        // h B-fragments: FIRST thing after the barrier (latency under MFMAs)
        const char* hb = reinterpret_cast<const char*>(s_h[cb]) + 16 * grp;
        f16x8 hf0 = ld_frag(hb);
        f16x8 hf1 = ld_frag(hb + 64);
        f16x8 hf2 = ld_frag(hb + 128);
        f16x8 hf3 = ld_frag(hb + 192);

        // acc seeded from x-projection (includes both biases)
        f32x4 acc0 = cvtq(xp.q0);
        f32x4 acc1 = cvtq(xp.q1);
        f32x4 acc2 = cvtq(xp.q2);
        f32x4 acc3 = cvtq(xp.q3);

        // prefetch xproj for t+2 (regs just freed; global, off the lgkm path)
        {
            int tn = t + 2; if (tn > TT - 1) tn = TT - 1;
            xp = ldxp(xpb, tn, jb);
        }

        // W_hh * h : 4 chains x 4 deep
        acc0 = __builtin_amdgcn_mfma_f32_16x16x32_f16(wfh[0][0], hf0, acc0, 0, 0, 0);
        acc1 = __builtin_amdgcn_mfma_f32_16x16x32_f16(wfh[1][0], hf0, acc1, 0, 0, 0);
        acc2 = __builtin_amdgcn_mfma_f32_16x16x32_f16(wfh[2][0], hf0, acc2, 0, 0, 0);
        acc3 = __builtin_amdgcn_mfma_f32_16x16x32_f16(wfh[3][0], hf0, acc3, 0, 0, 0);
        acc0 = __builtin_amdgcn_mfma_f32_16x16x32_f16(wfh[0][1], hf1, acc0, 0, 0, 0);
        acc1 = __builtin_amdgcn_mfma_f32_16x16x32_f16(wfh[1][1], hf1, acc1, 0, 0, 0);
        acc2 = __builtin_amdgcn_mfma_f32_16x16x32_f16(wfh[2][1], hf1, acc2, 0, 0, 0);
        acc3 = __builtin_amdgcn_mfma_f32_16x16x32_f16(wfh[3][1], hf1, acc3, 0, 0, 0);
        acc0 = __builtin_amdgcn_mfma_f32_16x16x32_f16(wfh[0][2], hf2, acc0, 0, 0, 0);
        acc1 = __builtin_amdgcn_mfma_f32_16x16x32_f16(wfh[1][2], hf2, acc1, 0, 0, 0);
        acc2 = __builtin_amdgcn_mfma_f32_16x16x32_f16(wfh[2][2], hf2, acc2, 0, 0, 0);
        acc3 = __builtin_amdgcn_mfma_f32_16x16x32_f16(wfh[3][2], hf2, acc3, 0, 0, 0);
        acc0 = __builtin_amdgcn_mfma_f32_16x16x32_f16(wfh[0][3], hf3, acc0, 0, 0, 0);
        acc1 = __builtin_amdgcn_mfma_f32_16x16x32_f16(wfh[1][3], hf3, acc1, 0, 0, 0);
        acc2 = __builtin_amdgcn_mfma_f32_16x16x32_f16(wfh[2][3], hf3, acc2, 0, 0, 0);
        acc3 = __builtin_amdgcn_mfma_f32_16x16x32_f16(wfh[3][3], hf3, acc3, 0, 0, 0);

        // select owned element
        const bool s1 = (lane & 1) != 0, s2 = (lane & 2) != 0;
        float p0 = s2 ? (s1 ? acc0[3] : acc0[2]) : (s1 ? acc0[1] : acc0[0]);
        float p1 = s2 ? (s1 ? acc1[3] : acc1[2]) : (s1 ? acc1[1] : acc1[0]);
        float p2 = s2 ? (s1 ? acc2[3] : acc2[2]) : (s1 ? acc2[1] : acc2[0]);
        float p3 = s2 ? (s1 ? acc3[3] : acc3[2]) : (s1 ? acc3[1] : acc3[0]);

        float ig = sigmoid_fast(p0);
        float fg = sigmoid_fast(p1);
        float gg = tanh_fast(p2);
        float og = sigmoid_fast(p3);

        c = fmaf(fg, c, ig * gg);
        float hv = og * tanh_fast(c);
        hlast = hv;

        if (writer) {
            reinterpret_cast<_Float16*>(s_h[nb])[jown] = (_Float16)hv;
            out_e[((size_t)b * TT + t) * HH + jown] = hv;
        }

        __syncthreads();
    };

    for (int t0 = 0; t0 < TT; t0 += 4) {
        step(t0 + 0, xf0);
        step(t0 + 1, xf1);
        step(t0 + 2, xf0);
        step(t0 + 3, xf1);
    }

    if (writer) out_h[(size_t)b * HH + jown] = hlast;
}

// ---------------------------------------------------------------------------
// Fallback (r5 kernel, 1269 us): used when the workspace is too small for
// the 256 MB xproj buffer.
// ---------------------------------------------------------------------------
__global__ __launch_bounds__(512, 2) void lstm_fused_kernel(
    const float* __restrict__ input, const float* __restrict__ h0,
    const float* __restrict__ c0, const float* __restrict__ W_ih,
    const float* __restrict__ W_hh, const float* __restrict__ b_ih,
    const float* __restrict__ b_hh, float* __restrict__ out)
{
    __shared__ __align__(16) h2 s_xh[2][96];

    const int tid  = threadIdx.x;
    const int b    = blockIdx.x;
    const int lane = tid & 63;
    const int w    = tid >> 6;
    const int grp  = lane >> 4;
    const int m    = lane & 15;
    const int r    = lane & 3;
    const int jb   = (w << 4) | (grp << 2);
    const int jown = jb | r;

    f16x8 wf[4][6];
#pragma unroll
    for (int g = 0; g < 4; ++g) {
        const int row = (g << 7) | (w << 4) | m;
#pragma unroll
        for (int kt = 0; kt < 6; ++kt) {
            const int k0 = 32 * kt + 8 * grp;
            const float* src = (k0 < II) ? (W_ih + (size_t)row * II + k0)
                                         : (W_hh + (size_t)row * HH + (k0 - II));
            const float4 v0 = reinterpret_cast<const float4*>(src)[0];
            const float4 v1 = reinterpret_cast<const float4*>(src)[1];
            f16x8 f;
            f[0] = (_Float16)v0.x; f[1] = (_Float16)v0.y;
            f[2] = (_Float16)v0.z; f[3] = (_Float16)v0.w;
            f[4] = (_Float16)v1.x; f[5] = (_Float16)v1.y;
            f[6] = (_Float16)v1.z; f[7] = (_Float16)v1.w;
            wf[g][kt] = f;
        }
    }

    f32x4 biasf[4];
#pragma unroll
    for (int g = 0; g < 4; ++g)
#pragma unroll
        for (int rr = 0; rr < 4; ++rr)
            biasf[g][rr] = b_ih[(g << 7) | (jb + rr)] + b_hh[(g << 7) | (jb + rr)];

    float c = c0[(size_t)b * HH + jown];
    if (tid < 64) {
        float2 hv = reinterpret_cast<const float2*>(h0 + (size_t)b * HH)[tid];
        s_xh[0][32 + tid] = mkh2(hv.x, hv.y);
    }

    const float2* xin = reinterpret_cast<const float2*>(input) + (size_t)b * TT * 32 + tid;
    float2 xb0, xb1, xb2, xb3;
    if (tid < 32) {
        xb0 = xin[(size_t)0 * 32];
        xb1 = xin[(size_t)1 * 32];
        xb2 = xin[(size_t)2 * 32];
        xb3 = xin[(size_t)3 * 32];
        s_xh[0][tid] = mkh2(xb0.x, xb0.y);
        xb0 = xin[(size_t)4 * 32];
    }
    __syncthreads();

    float* out_h = out;
    float* out_e = out + BB * HH;
    float hlast = 0.0f;
    const bool writer = (lane & 12) == 0;

    auto step = [&](int t, float2& xbn) {
        const int cb = t & 1, nb = cb ^ 1;
        if (tid < 32) {
            s_xh[nb][tid] = mkh2(xbn.x, xbn.y);
            int tn = t + 5; if (tn > TT - 1) tn = TT - 1;
            xbn = xin[(size_t)tn * 32];
        }
        const char* base = reinterpret_cast<const char*>(s_xh[cb]) + 16 * grp;
        f16x8 bf[6];
#pragma unroll
        for (int kt = 0; kt < 6; ++kt)
            bf[kt] = ld_frag(base + 64 * kt);
        f32x4 acc0 = biasf[0], acc1 = biasf[1], acc2 = biasf[2], acc3 = biasf[3];
#pragma unroll
        for (int kt = 0; kt < 6; ++kt) {
            acc0 = __builtin_amdgcn_mfma_f32_16x16x32_f16(wf[0][kt], bf[kt], acc0, 0, 0, 0);
            acc1 = __builtin_amdgcn_mfma_f32_16x16x32_f16(wf[1][kt], bf[kt], acc1, 0, 0, 0);
            acc2 = __builtin_amdgcn_mfma_f32_16x16x32_f16(wf[2][kt], bf[kt], acc2, 0, 0, 0);
            acc3 = __builtin_amdgcn_mfma_f32_16x16x32_f16(wf[3][kt], bf[kt], acc3, 0, 0, 0);
        }
        const bool s1 = (lane & 1) != 0, s2 = (lane & 2) != 0;
        float p0 = s2 ? (s1 ? acc0[3] : acc0[2]) : (s1 ? acc0[1] : acc0[0]);
        float p1 = s2 ? (s1 ? acc1[3] : acc1[2]) : (s1 ? acc1[1] : acc1[0]);
        float p2 = s2 ? (s1 ? acc2[3] : acc2[2]) : (s1 ? acc2[1] : acc2[0]);
        float p3 = s2 ? (s1 ? acc3[3] : acc3[2]) : (s1 ? acc3[1] : acc3[0]);
        float ig = sigmoid_fast(p0);
        float fg = sigmoid_fast(p1);
        float gg = tanh_fast(p2);
        float og = sigmoid_fast(p3);
        c = fmaf(fg, c, ig * gg);
        float hv = og * tanh_fast(c);
        hlast = hv;
        if (writer) {
            reinterpret_cast<_Float16*>(s_xh[nb])[II + jown] = (_Float16)hv;
            out_e[((size_t)b * TT + t) * HH + jown] = hv;
        }
        __syncthreads();
    };

    for (int t0 = 0; t0 < TT; t0 += 4) {
        step(t0 + 0, xb1);
        step(t0 + 1, xb2);
        step(t0 + 2, xb3);
        step(t0 + 3, xb0);
    }
    if (writer) out_h[(size_t)b * HH + jown] = hlast;
}

extern "C" void kernel_launch(void* const* d_in, const int* in_sizes, int n_in,
                              void* d_out, int out_size, void* d_ws, size_t ws_size,
                              hipStream_t stream) {
    const float* input = (const float*)d_in[0];
    const float* h0    = (const float*)d_in[1];
    const float* c0    = (const float*)d_in[2];
    const float* W_ih  = (const float*)d_in[3];
    const float* W_hh  = (const float*)d_in[4];
    const float* b_ih  = (const float*)d_in[5];
    const float* b_hh  = (const float*)d_in[6];
    float* out = (float*)d_out;

    const size_t need = (size_t)BB * TT * 512 * sizeof(_Float16);  // 256 MB
    if (d_ws != nullptr && ws_size >= need) {
        _Float16* xproj = (_Float16*)d_ws;
        hipLaunchKernelGGL(xproj_kernel, dim3(BB * (TT / 32)), dim3(512), 0, stream,
                           input, W_ih, b_ih, b_hh, xproj);
        hipLaunchKernelGGL(lstm_rec_kernel, dim3(BB), dim3(512), 0, stream,
                           xproj, h0, c0, W_hh, out);
    } else {
        hipLaunchKernelGGL(lstm_fused_kernel, dim3(BB), dim3(512), 0, stream,
                           input, h0, c0, W_ih, W_hh, b_ih, b_hh, out);
    }
}